// Round 12
// baseline (304.642 us; speedup 1.0000x reference)
//
#include <hip/hip_runtime.h>
#include <cstddef>
#include <cstdint>

#define B_ 4
#define N_ 16384
#define M_ 2048
#define C_ 128
#define NQ (B_*M_)         // 8192 queries
#define NSAMP 32
#define SAMP (NQ*NSAMP)    // 262144 samples
#define EPS_ 1e-5f
#define R2_ 9.0f

typedef short s8v  __attribute__((ext_vector_type(8)));
typedef short s4v  __attribute__((ext_vector_type(4)));
typedef float f32x4 __attribute__((ext_vector_type(4)));

#define ST_S0S 0
#define ST_S0Q 64
#define ST_S1S 128
#define ST_S1Q 136
#define ST_M1S 144
#define ST_M1Q 272
#define ST_M2S 400
#define ST_M2Q 656

__device__ __forceinline__ unsigned short f2bf(float f) {
    unsigned int u = __builtin_bit_cast(unsigned int, f);
    u += 0x7fffu + ((u >> 16) & 1u);     // round-to-nearest-even
    return (unsigned short)(u >> 16);
}
__device__ __forceinline__ float bf2f(unsigned short h) {
    unsigned int u = ((unsigned int)h) << 16;
    return __builtin_bit_cast(float, u);
}

// ---- prep: reorder+pad mlp_w0 (128x131 -> 128x160 bf16, feat-first), cast mlp_w1 (256x128 bf16)
__global__ void k_prep_w(const float* __restrict__ w0, const float* __restrict__ w1,
                         unsigned short* __restrict__ w0p, unsigned short* __restrict__ w1p) {
    int i = blockIdx.x * 256 + threadIdx.x;
    const int tot0 = 128 * 160;
    if (i < tot0) {
        int o = i / 160, c = i - o * 160;
        float v = 0.f;
        if (c < 128)      v = w0[o * 131 + 3 + c];
        else if (c < 131) v = w0[o * 131 + (c - 128)];
        w0p[i] = f2bf(v);
    }
    int j = i - tot0;
    if (j >= 0 && j < 256 * 128) w1p[j] = f2bf(w1[j]);
}

// ---- transpose backbone_features (B,C,N) f32 -> featT (B,N,C) bf16; vectorized write side
__global__ void k_transpose(const float* __restrict__ feat, unsigned short* __restrict__ featT) {
    __shared__ unsigned short tl[64][130];
    int b  = blockIdx.x >> 8;
    int n0 = (blockIdx.x & 255) * 64;
    const float* src = feat + (size_t)b * C_ * N_;
    int t = threadIdx.x;
    for (int i = 0; i < 32; ++i) {
        int lin = i * 256 + t;
        int c = lin >> 6, n = lin & 63;
        tl[n][c] = f2bf(src[(size_t)c * N_ + n0 + n]);
    }
    __syncthreads();
    unsigned short* dst = featT + ((size_t)b * N_ + n0) * 128;
    #pragma unroll
    for (int i = 0; i < 4; ++i) {
        int lin = i * 256 + t;
        int n = lin >> 4, cg = lin & 15;
        s8v v;
        #pragma unroll
        for (int e = 0; e < 8; ++e) v[e] = (short)tl[n][cg*8 + e];
        *(s8v*)(dst + (size_t)n * 128 + cg * 8) = v;
    }
}

// ---- shift MLP layer 0
__global__ void k_shift0(const float* __restrict__ xyz, const float* __restrict__ w0s,
                         float* __restrict__ t0, float* __restrict__ stats) {
    __shared__ float w[192];
    __shared__ float ps[4][64], pq[4][64];
    int t = threadIdx.x, wave = t >> 6, lane = t & 63;
    if (t < 192) w[t] = w0s[t];
    __syncthreads();
    int p = blockIdx.x * 256 + t;
    float q0 = xyz[p*3], q1 = xyz[p*3+1], q2 = xyz[p*3+2];
    float* orow = t0 + (size_t)p * 64;
    #pragma unroll
    for (int o = 0; o < 64; ++o) {
        float v = w[3*o]*q0 + w[3*o+1]*q1 + w[3*o+2]*q2;
        orow[o] = v;
        float s = v, sq = v * v;
        #pragma unroll
        for (int mk = 32; mk; mk >>= 1) { s += __shfl_xor(s, mk); sq += __shfl_xor(sq, mk); }
        if (lane == 0) { ps[wave][o] = s; pq[wave][o] = sq; }
    }
    __syncthreads();
    if (t < 64) {
        float s = ps[0][t] + ps[1][t] + ps[2][t] + ps[3][t];
        float q = pq[0][t] + pq[1][t] + pq[2][t] + pq[3][t];
        atomicAdd(&stats[ST_S0S + t], s);
        atomicAdd(&stats[ST_S0Q + t], q);
    }
}

// ---- shift layer 1
__global__ void k_shift1(const float* __restrict__ t0, const float* __restrict__ w1s,
                         const float* __restrict__ g0, const float* __restrict__ b0,
                         float* __restrict__ t1, float* __restrict__ stats) {
    __shared__ float aa[64], bb[64], wl[192];
    __shared__ float ps[4][3], pq[4][3];
    int t = threadIdx.x, wave = t >> 6, lane = t & 63;
    if (t < 64) {
        float mean = stats[ST_S0S + t] * (1.f / NQ);
        float var  = stats[ST_S0Q + t] * (1.f / NQ) - mean * mean;
        float a = g0[t] * rsqrtf(var + EPS_);
        aa[t] = a; bb[t] = b0[t] - mean * a;
    }
    if (t < 192) wl[t] = w1s[t];
    __syncthreads();
    int p = blockIdx.x * 256 + t;
    const f32x4* xr = (const f32x4*)(t0 + (size_t)p * 64);
    float v0 = 0.f, v1 = 0.f, v2 = 0.f;
    #pragma unroll
    for (int i = 0; i < 16; ++i) {
        f32x4 x = xr[i];
        #pragma unroll
        for (int j = 0; j < 4; ++j) {
            int c = 4*i + j;
            float h = fmaxf(0.f, aa[c] * x[j] + bb[c]);
            v0 += wl[c] * h; v1 += wl[64 + c] * h; v2 += wl[128 + c] * h;
        }
    }
    t1[p*3] = v0; t1[p*3+1] = v1; t1[p*3+2] = v2;
    float vv[3] = {v0, v1, v2};
    #pragma unroll
    for (int o = 0; o < 3; ++o) {
        float s = vv[o], q = vv[o] * vv[o];
        #pragma unroll
        for (int mk = 32; mk; mk >>= 1) { s += __shfl_xor(s, mk); q += __shfl_xor(q, mk); }
        if (lane == 0) { ps[wave][o] = s; pq[wave][o] = q; }
    }
    __syncthreads();
    if (t < 3) {
        float s = ps[0][t] + ps[1][t] + ps[2][t] + ps[3][t];
        float q = pq[0][t] + pq[1][t] + pq[2][t] + pq[3][t];
        atomicAdd(&stats[ST_S1S + t], s);
        atomicAdd(&stats[ST_S1Q + t], q);
    }
}

// ---- shift output
__global__ void k_shift2(const float* __restrict__ t1, const float* __restrict__ g1,
                         const float* __restrict__ b1, const float* __restrict__ stats,
                         float* __restrict__ nxyz) {
    int p = blockIdx.x * 256 + threadIdx.x;
    for (int o = 0; o < 3; ++o) {
        float mean = stats[ST_S1S + o] * (1.f / NQ);
        float var  = stats[ST_S1Q + o] * (1.f / NQ) - mean * mean;
        float a = g1[o] * rsqrtf(var + EPS_);
        float bbv = b1[o] - mean * a;
        nxyz[p*3+o] = fmaxf(0.f, a * t1[p*3+o] + bbv);
    }
}

// ---- ball query, wave-parallel, 4x unrolled
__global__ void k_ballq(const float* __restrict__ bxyz, const float* __restrict__ nxyz,
                        int* __restrict__ idxb) {
    int wq   = blockIdx.x * 4 + (threadIdx.x >> 6);
    int lane = threadIdx.x & 63;
    int b    = wq >> 11;
    float qx = nxyz[wq*3], qy = nxyz[wq*3+1], qz = nxyz[wq*3+2];
    float sq = __fadd_rn(__fadd_rn(__fmul_rn(qx,qx), __fmul_rn(qy,qy)), __fmul_rn(qz,qz));
    const float* bp = bxyz + (size_t)b * N_ * 3;
    int* op = idxb + (size_t)wq * 32;
    unsigned long long below = (lane == 63) ? ~0ull >> 1 : ((1ull << lane) - 1ull);
    int cnt = 0, first = 0;
    for (int j0 = 0; j0 < N_ && cnt < 32; j0 += 256) {
        float xs[4], ys[4], zs[4];
        #pragma unroll
        for (int u = 0; u < 4; ++u) {
            int j = j0 + u*64 + lane;
            xs[u] = bp[j*3]; ys[u] = bp[j*3+1]; zs[u] = bp[j*3+2];
        }
        #pragma unroll
        for (int u = 0; u < 4; ++u) {
            int j = j0 + u*64 + lane;
            float x = xs[u], y = ys[u], z = zs[u];
            float sx  = __fadd_rn(__fadd_rn(__fmul_rn(x,x), __fmul_rn(y,y)), __fmul_rn(z,z));
            float dot = __fadd_rn(__fadd_rn(__fmul_rn(qx,x), __fmul_rn(qy,y)), __fmul_rn(qz,z));
            float d2  = __fsub_rn(__fadd_rn(sq, sx), __fmul_rn(2.0f, dot));
            unsigned long long m = __ballot(d2 < R2_);
            if (cnt == 0 && m != 0ull) first = j0 + u*64 + __ffsll((long long)m) - 1;
            int pre = cnt + __popcll(m & below);
            if (((m >> lane) & 1ull) && pre < 32) op[pre] = j;
            cnt += __popcll(m);
        }
    }
    if (cnt < 32) {
        if (cnt == 0) first = 0;
        for (int k = cnt + lane; k < 32; k += 64) op[k] = first;
    }
}

// ---- GEMM1: FLIPPED, LDS-staged, QPB=4 (2 rounds of 2 queries) -> 2048 blocks
__global__ void __launch_bounds__(256)
k_gemm1(const unsigned short* __restrict__ featT, const float* __restrict__ bxyz,
        const float* __restrict__ nxyz, const int* __restrict__ idxb,
        const unsigned short* __restrict__ w0p, unsigned short* __restrict__ y1,
        float* __restrict__ stats) {
    __shared__ unsigned short gt[64][168];   // 64 samples x 160ch (+pad)
    __shared__ int pidx[128];
    __shared__ float nq[4][3];
    int tid  = threadIdx.x;
    int wave = tid >> 6, lane = tid & 63, quad = lane >> 4, l16 = lane & 15;
    int s2 = tid >> 2, part4 = tid & 3;
    int b = blockIdx.x >> 9;                 // 512 blocks per batch

    s8v bfr[2][5];
    #pragma unroll
    for (int g = 0; g < 2; ++g)
        #pragma unroll
        for (int kk = 0; kk < 5; ++kk)
            bfr[g][kk] = *(const s8v*)(w0p + (wave*32 + g*16 + l16)*160 + kk*32 + quad*8);

    if (tid < 128) pidx[tid] = idxb[blockIdx.x * 128 + tid];
    if (tid < 12) nq[tid / 3][tid % 3] = nxyz[blockIdx.x * 12 + tid];
    if (tid < 64)
        for (int c = 131; c < 160; ++c) gt[tid][c] = 0;
    __syncthreads();

    s8v pv[4]; float prel0 = 0.f, prel1 = 0.f, prel2 = 0.f;
    {
        int pp = pidx[s2];
        const unsigned short* src = featT + ((size_t)(b * N_ + pp)) * 128 + part4 * 32;
        pv[0] = *(const s8v*)src;        pv[1] = *(const s8v*)(src + 8);
        pv[2] = *(const s8v*)(src + 16); pv[3] = *(const s8v*)(src + 24);
        if (tid < 64) {
            int pq_ = pidx[tid];
            const float* bx = bxyz + (size_t)(b * N_ + pq_) * 3;
            int q = tid >> 5;
            prel0 = bx[0] - nq[q][0]; prel1 = bx[1] - nq[q][1]; prel2 = bx[2] - nq[q][2];
        }
    }
    float csum[2] = {}, csq[2] = {};

    for (int r = 0; r < 2; ++r) {
        __syncthreads();
        *(s8v*)&gt[s2][part4*32]      = pv[0];
        *(s8v*)&gt[s2][part4*32 + 8]  = pv[1];
        *(s8v*)&gt[s2][part4*32 + 16] = pv[2];
        *(s8v*)&gt[s2][part4*32 + 24] = pv[3];
        if (tid < 64) {
            gt[tid][128] = f2bf(prel0); gt[tid][129] = f2bf(prel1); gt[tid][130] = f2bf(prel2);
        }
        if (r + 1 < 2) {
            int pp = pidx[64 + s2];
            const unsigned short* src = featT + ((size_t)(b * N_ + pp)) * 128 + part4 * 32;
            pv[0] = *(const s8v*)src;        pv[1] = *(const s8v*)(src + 8);
            pv[2] = *(const s8v*)(src + 16); pv[3] = *(const s8v*)(src + 24);
            if (tid < 64) {
                int pq_ = pidx[64 + tid];
                const float* bx = bxyz + (size_t)(b * N_ + pq_) * 3;
                int q = 2 + (tid >> 5);
                prel0 = bx[0] - nq[q][0]; prel1 = bx[1] - nq[q][1]; prel2 = bx[2] - nq[q][2];
            }
        }
        __syncthreads();
        f32x4 acc[2][4] = {};
        #pragma unroll
        for (int kk = 0; kk < 5; ++kk) {
            s8v at[4];
            #pragma unroll
            for (int t = 0; t < 4; ++t)
                at[t] = *(const s8v*)&gt[t*16 + l16][kk*32 + quad*8];
            #pragma unroll
            for (int g = 0; g < 2; ++g)
                #pragma unroll
                for (int t = 0; t < 4; ++t)
                    acc[g][t] = __builtin_amdgcn_mfma_f32_16x16x32_bf16(at[t], bfr[g][kk], acc[g][t], 0, 0, 0);
        }
        size_t sbase = (size_t)blockIdx.x * 128 + r * 64;
        #pragma unroll
        for (int g = 0; g < 2; ++g) {
            int ch = wave*32 + g*16 + l16;
            #pragma unroll
            for (int t = 0; t < 4; ++t)
                #pragma unroll
                for (int rr = 0; rr < 4; ++rr) {
                    float v = acc[g][t][rr];
                    y1[(sbase + t*16 + quad*4 + rr) * 128 + ch] = f2bf(v);
                    csum[g] += v; csq[g] += v * v;
                }
        }
    }
    #pragma unroll
    for (int g = 0; g < 2; ++g) {
        float s = csum[g], q = csq[g];
        s += __shfl_xor(s, 16); s += __shfl_xor(s, 32);
        q += __shfl_xor(q, 16); q += __shfl_xor(q, 32);
        if (quad == 0) {
            int ch = wave*32 + g*16 + l16;
            atomicAdd(&stats[ST_M1S + ch], s);
            atomicAdd(&stats[ST_M1Q + ch], q);
        }
    }
}

// ---- GEMM2, single-stage, QPB=4 (128 samples staged once, 1 barrier, 2 rounds) -> 2048 blocks
__global__ void __launch_bounds__(256)
k_gemm2(const unsigned short* __restrict__ y1, const unsigned short* __restrict__ w1p,
        const float* __restrict__ g1m, const float* __restrict__ b1m,
        float* __restrict__ stats, float* __restrict__ mx, float* __restrict__ mn) {
    __shared__ unsigned short ht[128][136];   // 128 samples x 128ch (+pad)
    __shared__ float a1l[128], b1l[128];
    int tid = threadIdx.x;
    if (tid < 128) {
        float mean = stats[ST_M1S + tid] * (1.f / SAMP);
        float var  = stats[ST_M1Q + tid] * (1.f / SAMP) - mean * mean;
        float a = g1m[tid] * rsqrtf(var + EPS_);
        a1l[tid] = a; b1l[tid] = b1m[tid] - mean * a;
    }
    __syncthreads();
    int wave = tid >> 6, lane = tid & 63, quad = lane >> 4, l16 = lane & 15;
    int s = tid >> 3, part = tid & 7;

    float a1r[16], b1r[16];
    {
        const float* ap = &a1l[part * 16];
        const float* bp = &b1l[part * 16];
        #pragma unroll
        for (int i = 0; i < 16; ++i) { a1r[i] = ap[i]; b1r[i] = bp[i]; }
    }
    s8v bfr[4][4];
    #pragma unroll
    for (int g = 0; g < 4; ++g)
        #pragma unroll
        for (int kk = 0; kk < 4; ++kk)
            bfr[g][kk] = *(const s8v*)(w1p + (wave*64 + g*16 + l16)*128 + kk*32 + quad*8);

    // stage ALL 4 queries: issue all loads, then transform+store; one barrier
    size_t base = (size_t)blockIdx.x * 128;
    s8v rv[4][2];
    #pragma unroll
    for (int q = 0; q < 4; ++q) {
        const unsigned short* src = y1 + (base + q*32 + s) * 128 + part * 16;
        rv[q][0] = *(const s8v*)src; rv[q][1] = *(const s8v*)(src + 8);
    }
    #pragma unroll
    for (int q = 0; q < 4; ++q) {
        s8v o0, o1;
        #pragma unroll
        for (int e = 0; e < 8; ++e) {
            float f0 = bf2f((unsigned short)rv[q][0][e]);
            float f1 = bf2f((unsigned short)rv[q][1][e]);
            o0[e] = (short)f2bf(fmaxf(0.f, a1r[e]     * f0 + b1r[e]));
            o1[e] = (short)f2bf(fmaxf(0.f, a1r[8 + e] * f1 + b1r[8 + e]));
        }
        *(s8v*)&ht[q*32 + s][part*16]     = o0;
        *(s8v*)&ht[q*32 + s][part*16 + 8] = o1;
    }
    __syncthreads();   // the only in-loop barrier

    float csum[4] = {}, csq[4] = {};
    for (int r = 0; r < 2; ++r) {
        f32x4 acc[4][4] = {};
        #pragma unroll
        for (int kk = 0; kk < 4; ++kk) {
            s8v at[4];
            #pragma unroll
            for (int t = 0; t < 4; ++t)
                at[t] = *(const s8v*)&ht[r*64 + t*16 + l16][kk*32 + quad*8];
            #pragma unroll
            for (int g = 0; g < 4; ++g)
                #pragma unroll
                for (int t = 0; t < 4; ++t)
                    acc[g][t] = __builtin_amdgcn_mfma_f32_16x16x32_bf16(at[t], bfr[g][kk], acc[g][t], 0, 0, 0);
        }
        #pragma unroll
        for (int g = 0; g < 4; ++g) {
            float sacc = 0.f, qacc = 0.f;
            #pragma unroll
            for (int t = 0; t < 4; ++t)
                #pragma unroll
                for (int e = 0; e < 4; ++e) {
                    float v = acc[g][t][e];
                    sacc += v; qacc = __builtin_fmaf(v, v, qacc);
                }
            csum[g] += sacc; csq[g] += qacc;
            #pragma unroll
            for (int qh = 0; qh < 2; ++qh) {
                int gq = blockIdx.x * 4 + r*2 + qh;
                f32x4 v0 = acc[g][2*qh], v1 = acc[g][2*qh + 1];
                float hi = fmaxf(fmaxf(fmaxf(v0[0], v0[1]), fmaxf(v0[2], v0[3])),
                                 fmaxf(fmaxf(v1[0], v1[1]), fmaxf(v1[2], v1[3])));
                float lo = fminf(fminf(fminf(v0[0], v0[1]), fminf(v0[2], v0[3])),
                                 fminf(fminf(v1[0], v1[1]), fminf(v1[2], v1[3])));
                hi = fmaxf(hi, __shfl_xor(hi, 16)); hi = fmaxf(hi, __shfl_xor(hi, 32));
                lo = fminf(lo, __shfl_xor(lo, 16)); lo = fminf(lo, __shfl_xor(lo, 32));
                if (quad == 0) {
                    int c = wave*64 + g*16 + l16;
                    mx[(size_t)gq * 256 + c] = hi;
                    mn[(size_t)gq * 256 + c] = lo;
                }
            }
        }
    }
    #pragma unroll
    for (int g = 0; g < 4; ++g) {
        float sv = csum[g], q = csq[g];
        sv += __shfl_xor(sv, 16); sv += __shfl_xor(sv, 32);
        q  += __shfl_xor(q, 16);  q  += __shfl_xor(q, 32);
        if (quad == 0) {
            int c = wave*64 + g*16 + l16;
            atomicAdd(&stats[ST_M2S + c], sv);
            atomicAdd(&stats[ST_M2Q + c], q);
        }
    }
}

// ---- epilogue: out = relu(a2 * (a2>=0 ? mx : mn) + b2)
__global__ void k_final(const float* __restrict__ mx, const float* __restrict__ mn,
                        const float* __restrict__ g2m, const float* __restrict__ b2m,
                        const float* __restrict__ stats, float* __restrict__ out) {
    int i = blockIdx.x * 256 + threadIdx.x;
    int c = i & 255;
    float mean = stats[ST_M2S + c] * (1.f / SAMP);
    float var  = stats[ST_M2Q + c] * (1.f / SAMP) - mean * mean;
    float a = g2m[c] * rsqrtf(var + EPS_);
    float bb = b2m[c] - mean * a;
    float v = (a >= 0.f) ? mx[i] : mn[i];
    out[i] = fmaxf(0.f, a * v + bb);
}

extern "C" void kernel_launch(void* const* d_in, const int* in_sizes, int n_in,
                              void* d_out, int out_size, void* d_ws, size_t ws_size,
                              hipStream_t stream) {
    const float* ffps = (const float*)d_in[0];
    const float* bxyz = (const float*)d_in[1];
    const float* feat = (const float*)d_in[2];
    const float* sw0  = (const float*)d_in[3];
    const float* sg0  = (const float*)d_in[4];
    const float* sb0  = (const float*)d_in[5];
    const float* sw1  = (const float*)d_in[6];
    const float* sg1  = (const float*)d_in[7];
    const float* sb1  = (const float*)d_in[8];
    const float* mw0  = (const float*)d_in[9];
    const float* mg0  = (const float*)d_in[10];
    const float* mb0  = (const float*)d_in[11];
    const float* mw1  = (const float*)d_in[12];
    const float* mg1  = (const float*)d_in[13];
    const float* mb1  = (const float*)d_in[14];
    float* out = (float*)d_out;

    char* ws = (char*)d_ws;
    size_t off = 0;
    auto alloc = [&](size_t bytes) -> void* {
        void* p = ws + off;
        off += (bytes + 255) & ~(size_t)255;
        return p;
    };
    float*          stats = (float*)alloc(1024 * 4);
    float*          t0    = (float*)alloc((size_t)NQ * 64 * 4);
    float*          t1    = (float*)alloc((size_t)NQ * 3 * 4);
    float*          nxyz  = (float*)alloc((size_t)NQ * 3 * 4);
    int*            idxb  = (int*)alloc((size_t)NQ * 32 * 4);
    unsigned short* w0p   = (unsigned short*)alloc(128 * 160 * 2);
    unsigned short* w1p   = (unsigned short*)alloc(256 * 128 * 2);
    unsigned short* featT = (unsigned short*)alloc((size_t)B_ * N_ * 128 * 2);
    unsigned short* y1    = (unsigned short*)alloc((size_t)SAMP * 128 * 2);
    float*          mx    = (float*)alloc((size_t)NQ * 256 * 4);
    float*          mn    = (float*)alloc((size_t)NQ * 256 * 4);
    (void)in_sizes; (void)n_in; (void)out_size; (void)ws_size;

    hipMemsetAsync(stats, 0, 1024 * 4, stream);
    k_prep_w   <<<208, 256, 0, stream>>>(mw0, mw1, w0p, w1p);
    k_transpose<<<B_ * 256, 256, 0, stream>>>(feat, featT);
    k_shift0   <<<NQ / 256, 256, 0, stream>>>(ffps, sw0, t0, stats);
    k_shift1   <<<NQ / 256, 256, 0, stream>>>(t0, sw1, sg0, sb0, t1, stats);
    k_shift2   <<<NQ / 256, 256, 0, stream>>>(t1, sg1, sb1, stats, nxyz);
    k_ballq    <<<NQ / 4, 256, 0, stream>>>(bxyz, nxyz, idxb);
    k_gemm1    <<<NQ / 4, 256, 0, stream>>>(featT, bxyz, nxyz, idxb, w0p, y1, stats);
    k_gemm2    <<<NQ / 4, 256, 0, stream>>>(y1, w1p, mg0, mb0, stats, mx, mn);
    k_final    <<<NQ, 256, 0, stream>>>(mx, mn, mg1, mb1, stats, out);
}

// Round 13
// 248.059 us; speedup vs baseline: 1.2281x; 1.2281x over previous
//
#include <hip/hip_runtime.h>
#include <cstddef>
#include <cstdint>

#define B_ 4
#define N_ 16384
#define M_ 2048
#define C_ 128
#define NQ (B_*M_)         // 8192 queries
#define NSAMP 32
#define SAMP (NQ*NSAMP)    // 262144 samples
#define EPS_ 1e-5f
#define R2_ 9.0f

typedef short s8v  __attribute__((ext_vector_type(8)));
typedef short s4v  __attribute__((ext_vector_type(4)));
typedef float f32x4 __attribute__((ext_vector_type(4)));

// stats: 8 contention-split copies of a 1024-float block
#define ST_COPIES 8
#define ST_S0S 0
#define ST_S0Q 64
#define ST_S1S 128
#define ST_S1Q 136
#define ST_M1S 144
#define ST_M1Q 272
#define ST_M2S 400
#define ST_M2Q 656

__device__ __forceinline__ unsigned short f2bf(float f) {
    unsigned int u = __builtin_bit_cast(unsigned int, f);
    u += 0x7fffu + ((u >> 16) & 1u);     // round-to-nearest-even
    return (unsigned short)(u >> 16);
}
__device__ __forceinline__ float bf2f(unsigned short h) {
    unsigned int u = ((unsigned int)h) << 16;
    return __builtin_bit_cast(float, u);
}

// ---- prep: reorder+pad mlp_w0 (128x131 -> 128x160 bf16, feat-first), cast mlp_w1 (256x128 bf16)
__global__ void k_prep_w(const float* __restrict__ w0, const float* __restrict__ w1,
                         unsigned short* __restrict__ w0p, unsigned short* __restrict__ w1p) {
    int i = blockIdx.x * 256 + threadIdx.x;
    const int tot0 = 128 * 160;
    if (i < tot0) {
        int o = i / 160, c = i - o * 160;
        float v = 0.f;
        if (c < 128)      v = w0[o * 131 + 3 + c];
        else if (c < 131) v = w0[o * 131 + (c - 128)];
        w0p[i] = f2bf(v);
    }
    int j = i - tot0;
    if (j >= 0 && j < 256 * 128) w1p[j] = f2bf(w1[j]);
}

// ---- transpose backbone_features (B,C,N) f32 -> featT (B,N,C) bf16; vectorized write side
__global__ void k_transpose(const float* __restrict__ feat, unsigned short* __restrict__ featT) {
    __shared__ unsigned short tl[64][130];
    int b  = blockIdx.x >> 8;
    int n0 = (blockIdx.x & 255) * 64;
    const float* src = feat + (size_t)b * C_ * N_;
    int t = threadIdx.x;
    for (int i = 0; i < 32; ++i) {
        int lin = i * 256 + t;
        int c = lin >> 6, n = lin & 63;
        tl[n][c] = f2bf(src[(size_t)c * N_ + n0 + n]);
    }
    __syncthreads();
    unsigned short* dst = featT + ((size_t)b * N_ + n0) * 128;
    #pragma unroll
    for (int i = 0; i < 4; ++i) {
        int lin = i * 256 + t;
        int n = lin >> 4, cg = lin & 15;
        s8v v;
        #pragma unroll
        for (int e = 0; e < 8; ++e) v[e] = (short)tl[n][cg*8 + e];
        *(s8v*)(dst + (size_t)n * 128 + cg * 8) = v;
    }
}

// ---- shift MLP layer 0
__global__ void k_shift0(const float* __restrict__ xyz, const float* __restrict__ w0s,
                         float* __restrict__ t0, float* __restrict__ stats) {
    __shared__ float w[192];
    __shared__ float ps[4][64], pq[4][64];
    int t = threadIdx.x, wave = t >> 6, lane = t & 63;
    if (t < 192) w[t] = w0s[t];
    __syncthreads();
    int p = blockIdx.x * 256 + t;
    float q0 = xyz[p*3], q1 = xyz[p*3+1], q2 = xyz[p*3+2];
    float* orow = t0 + (size_t)p * 64;
    #pragma unroll
    for (int o = 0; o < 64; ++o) {
        float v = w[3*o]*q0 + w[3*o+1]*q1 + w[3*o+2]*q2;
        orow[o] = v;
        float s = v, sq = v * v;
        #pragma unroll
        for (int mk = 32; mk; mk >>= 1) { s += __shfl_xor(s, mk); sq += __shfl_xor(sq, mk); }
        if (lane == 0) { ps[wave][o] = s; pq[wave][o] = sq; }
    }
    __syncthreads();
    if (t < 64) {
        float s = ps[0][t] + ps[1][t] + ps[2][t] + ps[3][t];
        float q = pq[0][t] + pq[1][t] + pq[2][t] + pq[3][t];
        atomicAdd(&stats[ST_S0S + t], s);
        atomicAdd(&stats[ST_S0Q + t], q);
    }
}

// ---- shift layer 1
__global__ void k_shift1(const float* __restrict__ t0, const float* __restrict__ w1s,
                         const float* __restrict__ g0, const float* __restrict__ b0,
                         float* __restrict__ t1, float* __restrict__ stats) {
    __shared__ float aa[64], bb[64], wl[192];
    __shared__ float ps[4][3], pq[4][3];
    int t = threadIdx.x, wave = t >> 6, lane = t & 63;
    if (t < 64) {
        float mean = stats[ST_S0S + t] * (1.f / NQ);
        float var  = stats[ST_S0Q + t] * (1.f / NQ) - mean * mean;
        float a = g0[t] * rsqrtf(var + EPS_);
        aa[t] = a; bb[t] = b0[t] - mean * a;
    }
    if (t < 192) wl[t] = w1s[t];
    __syncthreads();
    int p = blockIdx.x * 256 + t;
    const f32x4* xr = (const f32x4*)(t0 + (size_t)p * 64);
    float v0 = 0.f, v1 = 0.f, v2 = 0.f;
    #pragma unroll
    for (int i = 0; i < 16; ++i) {
        f32x4 x = xr[i];
        #pragma unroll
        for (int j = 0; j < 4; ++j) {
            int c = 4*i + j;
            float h = fmaxf(0.f, aa[c] * x[j] + bb[c]);
            v0 += wl[c] * h; v1 += wl[64 + c] * h; v2 += wl[128 + c] * h;
        }
    }
    t1[p*3] = v0; t1[p*3+1] = v1; t1[p*3+2] = v2;
    float vv[3] = {v0, v1, v2};
    #pragma unroll
    for (int o = 0; o < 3; ++o) {
        float s = vv[o], q = vv[o] * vv[o];
        #pragma unroll
        for (int mk = 32; mk; mk >>= 1) { s += __shfl_xor(s, mk); q += __shfl_xor(q, mk); }
        if (lane == 0) { ps[wave][o] = s; pq[wave][o] = q; }
    }
    __syncthreads();
    if (t < 3) {
        float s = ps[0][t] + ps[1][t] + ps[2][t] + ps[3][t];
        float q = pq[0][t] + pq[1][t] + pq[2][t] + pq[3][t];
        atomicAdd(&stats[ST_S1S + t], s);
        atomicAdd(&stats[ST_S1Q + t], q);
    }
}

// ---- shift output
__global__ void k_shift2(const float* __restrict__ t1, const float* __restrict__ g1,
                         const float* __restrict__ b1, const float* __restrict__ stats,
                         float* __restrict__ nxyz) {
    int p = blockIdx.x * 256 + threadIdx.x;
    for (int o = 0; o < 3; ++o) {
        float mean = stats[ST_S1S + o] * (1.f / NQ);
        float var  = stats[ST_S1Q + o] * (1.f / NQ) - mean * mean;
        float a = g1[o] * rsqrtf(var + EPS_);
        float bbv = b1[o] - mean * a;
        nxyz[p*3+o] = fmaxf(0.f, a * t1[p*3+o] + bbv);
    }
}

// ---- ball query, wave-parallel, 8x unrolled (24 independent loads in flight)
__global__ void k_ballq(const float* __restrict__ bxyz, const float* __restrict__ nxyz,
                        int* __restrict__ idxb) {
    int wq   = blockIdx.x * 4 + (threadIdx.x >> 6);
    int lane = threadIdx.x & 63;
    int b    = wq >> 11;
    float qx = nxyz[wq*3], qy = nxyz[wq*3+1], qz = nxyz[wq*3+2];
    float sq = __fadd_rn(__fadd_rn(__fmul_rn(qx,qx), __fmul_rn(qy,qy)), __fmul_rn(qz,qz));
    const float* bp = bxyz + (size_t)b * N_ * 3;
    int* op = idxb + (size_t)wq * 32;
    unsigned long long below = (lane == 63) ? ~0ull >> 1 : ((1ull << lane) - 1ull);
    int cnt = 0, first = 0;
    for (int j0 = 0; j0 < N_ && cnt < 32; j0 += 512) {
        float xs[8], ys[8], zs[8];
        #pragma unroll
        for (int u = 0; u < 8; ++u) {
            int j = j0 + u*64 + lane;
            xs[u] = bp[j*3]; ys[u] = bp[j*3+1]; zs[u] = bp[j*3+2];
        }
        #pragma unroll
        for (int u = 0; u < 8; ++u) {
            int j = j0 + u*64 + lane;
            float x = xs[u], y = ys[u], z = zs[u];
            float sx  = __fadd_rn(__fadd_rn(__fmul_rn(x,x), __fmul_rn(y,y)), __fmul_rn(z,z));
            float dot = __fadd_rn(__fadd_rn(__fmul_rn(qx,x), __fmul_rn(qy,y)), __fmul_rn(qz,z));
            float d2  = __fsub_rn(__fadd_rn(sq, sx), __fmul_rn(2.0f, dot));
            unsigned long long m = __ballot(d2 < R2_);
            if (cnt == 0 && m != 0ull) first = j0 + u*64 + __ffsll((long long)m) - 1;
            int pre = cnt + __popcll(m & below);
            if (((m >> lane) & 1ull) && pre < 32) op[pre] = j;
            cnt += __popcll(m);
        }
    }
    if (cnt < 32) {
        if (cnt == 0) first = 0;
        for (int k = cnt + lane; k < 32; k += 64) op[k] = first;
    }
}

// ---- GEMM1 (QPB=8, grid 1024): FLIPPED, LDS-staged, 2 queries/round, register prefetch.
// Stats atomics go to the block's contention-split stats copy.
__global__ void __launch_bounds__(256)
k_gemm1(const unsigned short* __restrict__ featT, const float* __restrict__ bxyz,
        const float* __restrict__ nxyz, const int* __restrict__ idxb,
        const unsigned short* __restrict__ w0p, unsigned short* __restrict__ y1,
        float* __restrict__ stats) {
    __shared__ unsigned short gt[64][168];   // 64 samples x 160ch (+pad)
    __shared__ int pidx[256];
    __shared__ float nq[8][3];
    int tid  = threadIdx.x;
    int wave = tid >> 6, lane = tid & 63, quad = lane >> 4, l16 = lane & 15;
    int s2 = tid >> 2, part4 = tid & 3;
    int b = blockIdx.x >> 8;
    float* stc = stats + (size_t)(blockIdx.x & (ST_COPIES-1)) * 1024;

    s8v bfr[2][5];
    #pragma unroll
    for (int g = 0; g < 2; ++g)
        #pragma unroll
        for (int kk = 0; kk < 5; ++kk)
            bfr[g][kk] = *(const s8v*)(w0p + (wave*32 + g*16 + l16)*160 + kk*32 + quad*8);

    pidx[tid] = idxb[blockIdx.x * 256 + tid];
    if (tid < 24) nq[tid / 3][tid % 3] = nxyz[blockIdx.x * 24 + tid];
    if (tid < 64)
        for (int c = 131; c < 160; ++c) gt[tid][c] = 0;
    __syncthreads();

    s8v pv[4]; float prel0 = 0.f, prel1 = 0.f, prel2 = 0.f;
    {
        int pp = pidx[s2];
        const unsigned short* src = featT + ((size_t)(b * N_ + pp)) * 128 + part4 * 32;
        pv[0] = *(const s8v*)src;        pv[1] = *(const s8v*)(src + 8);
        pv[2] = *(const s8v*)(src + 16); pv[3] = *(const s8v*)(src + 24);
        if (tid < 64) {
            int pq_ = pidx[tid];
            const float* bx = bxyz + (size_t)(b * N_ + pq_) * 3;
            int q = tid >> 5;
            prel0 = bx[0] - nq[q][0]; prel1 = bx[1] - nq[q][1]; prel2 = bx[2] - nq[q][2];
        }
    }
    float csum[2] = {}, csq[2] = {};

    for (int r = 0; r < 4; ++r) {
        __syncthreads();
        *(s8v*)&gt[s2][part4*32]      = pv[0];
        *(s8v*)&gt[s2][part4*32 + 8]  = pv[1];
        *(s8v*)&gt[s2][part4*32 + 16] = pv[2];
        *(s8v*)&gt[s2][part4*32 + 24] = pv[3];
        if (tid < 64) {
            gt[tid][128] = f2bf(prel0); gt[tid][129] = f2bf(prel1); gt[tid][130] = f2bf(prel2);
        }
        if (r + 1 < 4) {
            int pp = pidx[(r+1)*64 + s2];
            const unsigned short* src = featT + ((size_t)(b * N_ + pp)) * 128 + part4 * 32;
            pv[0] = *(const s8v*)src;        pv[1] = *(const s8v*)(src + 8);
            pv[2] = *(const s8v*)(src + 16); pv[3] = *(const s8v*)(src + 24);
            if (tid < 64) {
                int pq_ = pidx[(r+1)*64 + tid];
                const float* bx = bxyz + (size_t)(b * N_ + pq_) * 3;
                int q = (r+1)*2 + (tid >> 5);
                prel0 = bx[0] - nq[q][0]; prel1 = bx[1] - nq[q][1]; prel2 = bx[2] - nq[q][2];
            }
        }
        __syncthreads();
        f32x4 acc[2][4] = {};
        #pragma unroll
        for (int kk = 0; kk < 5; ++kk) {
            s8v at[4];
            #pragma unroll
            for (int t = 0; t < 4; ++t)
                at[t] = *(const s8v*)&gt[t*16 + l16][kk*32 + quad*8];
            #pragma unroll
            for (int g = 0; g < 2; ++g)
                #pragma unroll
                for (int t = 0; t < 4; ++t)
                    acc[g][t] = __builtin_amdgcn_mfma_f32_16x16x32_bf16(at[t], bfr[g][kk], acc[g][t], 0, 0, 0);
        }
        size_t sbase = (size_t)blockIdx.x * 256 + r * 64;
        #pragma unroll
        for (int g = 0; g < 2; ++g) {
            int ch = wave*32 + g*16 + l16;
            #pragma unroll
            for (int t = 0; t < 4; ++t)
                #pragma unroll
                for (int rr = 0; rr < 4; ++rr) {
                    float v = acc[g][t][rr];
                    y1[(sbase + t*16 + quad*4 + rr) * 128 + ch] = f2bf(v);
                    csum[g] += v; csq[g] += v * v;
                }
        }
    }
    #pragma unroll
    for (int g = 0; g < 2; ++g) {
        float s = csum[g], q = csq[g];
        s += __shfl_xor(s, 16); s += __shfl_xor(s, 32);
        q += __shfl_xor(q, 16); q += __shfl_xor(q, 32);
        if (quad == 0) {
            int ch = wave*32 + g*16 + l16;
            atomicAdd(&stc[ST_M1S + ch], s);
            atomicAdd(&stc[ST_M1Q + ch], q);
        }
    }
}

// ---- GEMM2 (QPB=8, grid 1024): single-stage (all 256 samples staged once, 1 barrier),
// 4 barrier-free MFMA rounds. Reads 8 stats copies for bn1; writes to its split copy.
__global__ void __launch_bounds__(256)
k_gemm2(const unsigned short* __restrict__ y1, const unsigned short* __restrict__ w1p,
        const float* __restrict__ g1m, const float* __restrict__ b1m,
        float* __restrict__ stats, float* __restrict__ mx, float* __restrict__ mn) {
    __shared__ unsigned short ht[256][136];   // 256 samples x 128ch (+pad)
    __shared__ float a1l[128], b1l[128];
    int tid = threadIdx.x;
    float* stc = stats + (size_t)(blockIdx.x & (ST_COPIES-1)) * 1024;
    if (tid < 128) {
        float ssum = 0.f, ssq = 0.f;
        #pragma unroll
        for (int c8 = 0; c8 < ST_COPIES; ++c8) {
            ssum += stats[c8*1024 + ST_M1S + tid];
            ssq  += stats[c8*1024 + ST_M1Q + tid];
        }
        float mean = ssum * (1.f / SAMP);
        float var  = ssq  * (1.f / SAMP) - mean * mean;
        float a = g1m[tid] * rsqrtf(var + EPS_);
        a1l[tid] = a; b1l[tid] = b1m[tid] - mean * a;
    }
    __syncthreads();
    int wave = tid >> 6, lane = tid & 63, quad = lane >> 4, l16 = lane & 15;
    int s = tid >> 3, part = tid & 7;

    float a1r[16], b1r[16];
    {
        const float* ap = &a1l[part * 16];
        const float* bp = &b1l[part * 16];
        #pragma unroll
        for (int i = 0; i < 16; ++i) { a1r[i] = ap[i]; b1r[i] = bp[i]; }
    }
    s8v bfr[4][4];
    #pragma unroll
    for (int g = 0; g < 4; ++g)
        #pragma unroll
        for (int kk = 0; kk < 4; ++kk)
            bfr[g][kk] = *(const s8v*)(w1p + (wave*64 + g*16 + l16)*128 + kk*32 + quad*8);

    // stage ALL 8 queries: issue all loads, then transform+store; one barrier
    size_t base = (size_t)blockIdx.x * 256;
    s8v rv[8][2];
    #pragma unroll
    for (int q = 0; q < 8; ++q) {
        const unsigned short* src = y1 + (base + q*32 + s) * 128 + part * 16;
        rv[q][0] = *(const s8v*)src; rv[q][1] = *(const s8v*)(src + 8);
    }
    #pragma unroll
    for (int q = 0; q < 8; ++q) {
        s8v o0, o1;
        #pragma unroll
        for (int e = 0; e < 8; ++e) {
            float f0 = bf2f((unsigned short)rv[q][0][e]);
            float f1 = bf2f((unsigned short)rv[q][1][e]);
            o0[e] = (short)f2bf(fmaxf(0.f, a1r[e]     * f0 + b1r[e]));
            o1[e] = (short)f2bf(fmaxf(0.f, a1r[8 + e] * f1 + b1r[8 + e]));
        }
        *(s8v*)&ht[q*32 + s][part*16]     = o0;
        *(s8v*)&ht[q*32 + s][part*16 + 8] = o1;
    }
    __syncthreads();   // the only in-loop barrier

    float csum[4] = {}, csq[4] = {};
    for (int r = 0; r < 4; ++r) {
        f32x4 acc[4][4] = {};
        #pragma unroll
        for (int kk = 0; kk < 4; ++kk) {
            s8v at[4];
            #pragma unroll
            for (int t = 0; t < 4; ++t)
                at[t] = *(const s8v*)&ht[r*64 + t*16 + l16][kk*32 + quad*8];
            #pragma unroll
            for (int g = 0; g < 4; ++g)
                #pragma unroll
                for (int t = 0; t < 4; ++t)
                    acc[g][t] = __builtin_amdgcn_mfma_f32_16x16x32_bf16(at[t], bfr[g][kk], acc[g][t], 0, 0, 0);
        }
        #pragma unroll
        for (int g = 0; g < 4; ++g) {
            float sacc = 0.f, qacc = 0.f;
            #pragma unroll
            for (int t = 0; t < 4; ++t)
                #pragma unroll
                for (int e = 0; e < 4; ++e) {
                    float v = acc[g][t][e];
                    sacc += v; qacc = __builtin_fmaf(v, v, qacc);
                }
            csum[g] += sacc; csq[g] += qacc;
            #pragma unroll
            for (int qh = 0; qh < 2; ++qh) {
                int gq = blockIdx.x * 8 + r*2 + qh;
                f32x4 v0 = acc[g][2*qh], v1 = acc[g][2*qh + 1];
                float hi = fmaxf(fmaxf(fmaxf(v0[0], v0[1]), fmaxf(v0[2], v0[3])),
                                 fmaxf(fmaxf(v1[0], v1[1]), fmaxf(v1[2], v1[3])));
                float lo = fminf(fminf(fminf(v0[0], v0[1]), fminf(v0[2], v0[3])),
                                 fminf(fminf(v1[0], v1[1]), fminf(v1[2], v1[3])));
                hi = fmaxf(hi, __shfl_xor(hi, 16)); hi = fmaxf(hi, __shfl_xor(hi, 32));
                lo = fminf(lo, __shfl_xor(lo, 16)); lo = fminf(lo, __shfl_xor(lo, 32));
                if (quad == 0) {
                    int c = wave*64 + g*16 + l16;
                    mx[(size_t)gq * 256 + c] = hi;
                    mn[(size_t)gq * 256 + c] = lo;
                }
            }
        }
    }
    #pragma unroll
    for (int g = 0; g < 4; ++g) {
        float sv = csum[g], q = csq[g];
        sv += __shfl_xor(sv, 16); sv += __shfl_xor(sv, 32);
        q  += __shfl_xor(q, 16);  q  += __shfl_xor(q, 32);
        if (quad == 0) {
            int c = wave*64 + g*16 + l16;
            atomicAdd(&stc[ST_M2S + c], sv);
            atomicAdd(&stc[ST_M2Q + c], q);
        }
    }
}

// ---- epilogue: out = relu(a2 * (a2>=0 ? mx : mn) + b2)  (sums 8 stats copies)
__global__ void k_final(const float* __restrict__ mx, const float* __restrict__ mn,
                        const float* __restrict__ g2m, const float* __restrict__ b2m,
                        const float* __restrict__ stats, float* __restrict__ out) {
    int i = blockIdx.x * 256 + threadIdx.x;
    int c = i & 255;
    float ssum = 0.f, ssq = 0.f;
    #pragma unroll
    for (int c8 = 0; c8 < ST_COPIES; ++c8) {
        ssum += stats[c8*1024 + ST_M2S + c];
        ssq  += stats[c8*1024 + ST_M2Q + c];
    }
    float mean = ssum * (1.f / SAMP);
    float var  = ssq  * (1.f / SAMP) - mean * mean;
    float a = g2m[c] * rsqrtf(var + EPS_);
    float bb = b2m[c] - mean * a;
    float v = (a >= 0.f) ? mx[i] : mn[i];
    out[i] = fmaxf(0.f, a * v + bb);
}

extern "C" void kernel_launch(void* const* d_in, const int* in_sizes, int n_in,
                              void* d_out, int out_size, void* d_ws, size_t ws_size,
                              hipStream_t stream) {
    const float* ffps = (const float*)d_in[0];
    const float* bxyz = (const float*)d_in[1];
    const float* feat = (const float*)d_in[2];
    const float* sw0  = (const float*)d_in[3];
    const float* sg0  = (const float*)d_in[4];
    const float* sb0  = (const float*)d_in[5];
    const float* sw1  = (const float*)d_in[6];
    const float* sg1  = (const float*)d_in[7];
    const float* sb1  = (const float*)d_in[8];
    const float* mw0  = (const float*)d_in[9];
    const float* mg0  = (const float*)d_in[10];
    const float* mb0  = (const float*)d_in[11];
    const float* mw1  = (const float*)d_in[12];
    const float* mg1  = (const float*)d_in[13];
    const float* mb1  = (const float*)d_in[14];
    float* out = (float*)d_out;

    char* ws = (char*)d_ws;
    size_t off = 0;
    auto alloc = [&](size_t bytes) -> void* {
        void* p = ws + off;
        off += (bytes + 255) & ~(size_t)255;
        return p;
    };
    float*          stats = (float*)alloc(ST_COPIES * 1024 * 4);
    float*          t0    = (float*)alloc((size_t)NQ * 64 * 4);
    float*          t1    = (float*)alloc((size_t)NQ * 3 * 4);
    float*          nxyz  = (float*)alloc((size_t)NQ * 3 * 4);
    int*            idxb  = (int*)alloc((size_t)NQ * 32 * 4);
    unsigned short* w0p   = (unsigned short*)alloc(128 * 160 * 2);
    unsigned short* w1p   = (unsigned short*)alloc(256 * 128 * 2);
    unsigned short* featT = (unsigned short*)alloc((size_t)B_ * N_ * 128 * 2);
    unsigned short* y1    = (unsigned short*)alloc((size_t)SAMP * 128 * 2);
    float*          mx    = (float*)alloc((size_t)NQ * 256 * 4);
    float*          mn    = (float*)alloc((size_t)NQ * 256 * 4);
    (void)in_sizes; (void)n_in; (void)out_size; (void)ws_size;

    hipMemsetAsync(stats, 0, ST_COPIES * 1024 * 4, stream);
    k_prep_w   <<<208, 256, 0, stream>>>(mw0, mw1, w0p, w1p);
    k_transpose<<<B_ * 256, 256, 0, stream>>>(feat, featT);
    k_shift0   <<<NQ / 256, 256, 0, stream>>>(ffps, sw0, t0, stats);
    k_shift1   <<<NQ / 256, 256, 0, stream>>>(t0, sw1, sg0, sb0, t1, stats);
    k_shift2   <<<NQ / 256, 256, 0, stream>>>(t1, sg1, sb1, stats, nxyz);
    k_ballq    <<<NQ / 4, 256, 0, stream>>>(bxyz, nxyz, idxb);
    k_gemm1    <<<NQ / 8, 256, 0, stream>>>(featT, bxyz, nxyz, idxb, w0p, y1, stats);
    k_gemm2    <<<NQ / 8, 256, 0, stream>>>(y1, w1p, mg0, mb0, stats, mx, mn);
    k_final    <<<NQ, 256, 0, stream>>>(mx, mn, mg1, mb1, stats, out);
}